// Round 6
// baseline (353.922 us; speedup 1.0000x reference)
//
#include <hip/hip_runtime.h>
#include <hip/hip_bf16.h>
#include <hip/hip_fp16.h>
#include <stdint.h>

#define NNODES 100000
#define HID 128
#define NEDGES 1000000

typedef __attribute__((ext_vector_type(8))) short short8;
typedef __attribute__((ext_vector_type(4))) float floatx4;
typedef _Float16 f16x2 __attribute__((ext_vector_type(2)));

__device__ __forceinline__ unsigned short bf16_rn(float x) {
  unsigned u = __builtin_bit_cast(unsigned, x);
  u += 0x7fffu + ((u >> 16) & 1u);
  return (unsigned short)(u >> 16);
}
__device__ __forceinline__ float bf16_to_f(unsigned short h) {
  unsigned u = ((unsigned)h) << 16;
  return __builtin_bit_cast(float, u);
}

// ---------------- Kernel 0: prep ----------------
// blocks [0,6250): emb (fp32, 12.8M elems) -> Ahi/Alo bf16 hi/lo split,
//                  row-major [node][k] (flat copy, 8 elems/thread).
// blocks [6250,6266): pack B = [W1_top | W1_bot] into MFMA fragment order,
//                  bf16 hi/lo. Fragment: B[k=(lane>>4)*8+j][n=lane&15],
//                  element base ((ct*4+ks)*64+lane)*8.
// block 6250 thread 0 also zeroes accum.
__global__ __launch_bounds__(256) void prep_kernel(
    const float* __restrict__ emb, const float* __restrict__ W1,
    short* __restrict__ Ahi, short* __restrict__ Alo,
    short* __restrict__ Bhi, short* __restrict__ Blo,
    float* __restrict__ accum) {
  const int b = blockIdx.x;
  if (b < 6250) {
    const size_t i = ((size_t)b * 256 + threadIdx.x) * 8;
    const floatx4 v0 = *(const floatx4*)(emb + i);
    const floatx4 v1 = *(const floatx4*)(emb + i + 4);
    float x[8] = {v0.x, v0.y, v0.z, v0.w, v1.x, v1.y, v1.z, v1.w};
    short8 h, l;
#pragma unroll
    for (int j = 0; j < 8; ++j) {
      const unsigned short hh = bf16_rn(x[j]);
      h[j] = (short)hh;
      l[j] = (short)bf16_rn(x[j] - bf16_to_f(hh));
    }
    *(short8*)(Ahi + i) = h;
    *(short8*)(Alo + i) = l;
  } else {
    if (b == 6250 && threadIdx.x == 0) accum[0] = 0.f;
    const int t = (b - 6250) * 256 + threadIdx.x;  // 0..4095
    const int lane = t & 63;
    const int ks = (t >> 6) & 3;
    const int ct = t >> 8;
    const int n = ct * 16 + (lane & 15);
    const int kb = ks * 32 + ((lane >> 4) * 8);
    short8 h, l;
#pragma unroll
    for (int j = 0; j < 8; ++j) {
      const int k = kb + j;
      const float v = (n < HID) ? W1[(size_t)k * HID + n]
                                : W1[(size_t)(HID + k) * HID + (n - HID)];
      const unsigned short hh = bf16_rn(v);
      h[j] = (short)hh;
      l[j] = (short)bf16_rn(v - bf16_to_f(hh));
    }
    *(short8*)(Bhi + (size_t)t * 8) = h;
    *(short8*)(Blo + (size_t)t * 8) = l;
  }
}

// ---------------- Kernel 1: node projection via MFMA (bf16 hi/lo split) ----
// Block: 64 rows x 256 cols. A fragments read DIRECTLY from pre-split global
// Ahi/Alo (16B/lane, 128B lines fully consumed; 4 waves reuse via L1).
// No LDS, no barriers in the K-path. P[m][n] fp16 store via LDS epilogue.
__global__ __launch_bounds__(256) void project_kernel(
    const short* __restrict__ Ahi, const short* __restrict__ Alo,
    const short* __restrict__ Bhi, const short* __restrict__ Blo,
    __half* __restrict__ P) {
  __shared__ __half Co[64 * 264];  // 33792 B

  const int t = threadIdx.x;
  const int lane = t & 63;
  const int w = t >> 6;
  const int l16 = lane & 15;
  const int q = lane >> 4;
  const int row0 = blockIdx.x * 64;

  floatx4 acc[4][4] = {};  // [rt][ct]

#pragma unroll
  for (int ks = 0; ks < 4; ++ks) {
    short8 bh[4], bl[4];
#pragma unroll
    for (int ct = 0; ct < 4; ++ct) {
      const size_t idx = (size_t)(((w * 4 + ct) * 4 + ks) * 64 + lane) * 8;
      bh[ct] = *(const short8*)(Bhi + idx);
      bl[ct] = *(const short8*)(Blo + idx);
    }
#pragma unroll
    for (int rt = 0; rt < 4; ++rt) {
      const size_t la = (size_t)(row0 + rt * 16 + l16) * 128 + ks * 32 + q * 8;
      const short8 ah = *(const short8*)(Ahi + la);
      const short8 al = *(const short8*)(Alo + la);
#pragma unroll
      for (int ct = 0; ct < 4; ++ct) {
        acc[rt][ct] = __builtin_amdgcn_mfma_f32_16x16x32_bf16(ah, bh[ct], acc[rt][ct], 0, 0, 0);
        acc[rt][ct] = __builtin_amdgcn_mfma_f32_16x16x32_bf16(al, bh[ct], acc[rt][ct], 0, 0, 0);
        acc[rt][ct] = __builtin_amdgcn_mfma_f32_16x16x32_bf16(ah, bl[ct], acc[rt][ct], 0, 0, 0);
      }
    }
  }

  // epilogue: C/D layout col=lane&15, row=(lane>>4)*4+reg -> LDS -> coalesced.
  // Waves write disjoint column ranges; one barrier before the gather-store.
#pragma unroll
  for (int rt = 0; rt < 4; ++rt)
#pragma unroll
    for (int ct = 0; ct < 4; ++ct)
#pragma unroll
      for (int r = 0; r < 4; ++r) {
        const int row = rt * 16 + q * 4 + r;
        const int col = w * 64 + ct * 16 + l16;
        Co[row * 264 + col] = __float2half(acc[rt][ct][r]);
      }
  __syncthreads();
#pragma unroll
  for (int i = 0; i < 8; ++i) {
    const int chunk = t + i * 256;  // 2048 chunks of 16B, 32 per row
    const int row = chunk >> 5;
    const int cx = chunk & 31;
    if (row0 + row < NNODES) {
      const floatx4 v = *(const floatx4*)&Co[row * 264 + cx * 8];
      *(floatx4*)(P + (size_t)(row0 + row) * 256 + cx * 8) = v;
    }
  }
}

// ---------------- Kernel 2: per-edge MLP + exp --------------------
// Exact-fit grid: 15625 blocks x 4 waves x 16 edges = 1,000,000. No loop,
// no bounds checks. 16 lanes/edge, 8 halfs/lane (dwordx4 gathers),
// packed-half math + v_dot2_f32_f16, 4-shuffle reduce per 4 edges.
__global__ __launch_bounds__(256) void edge_kernel(
    const __half* __restrict__ P, const int* __restrict__ lm,
    const float* __restrict__ b1, const float* __restrict__ W2,
    const float* __restrict__ b2, float* __restrict__ explog,
    float* __restrict__ sum_accum) {
  const int lane = threadIdx.x & 63;
  const int wid = threadIdx.x >> 6;
  const int g = lane >> 4;    // edge sub-group 0..3
  const int l16 = lane & 15;
  const int c = l16 * 8;      // 8 halfs per lane

  f16x2 b1h[4], w2h[4];
  {
    const floatx4 b1a = *(const floatx4*)(b1 + c);
    const floatx4 b1b = *(const floatx4*)(b1 + c + 4);
    const floatx4 w2a = *(const floatx4*)(W2 + c);
    const floatx4 w2b = *(const floatx4*)(W2 + c + 4);
    b1h[0] = f16x2{(_Float16)b1a.x, (_Float16)b1a.y};
    b1h[1] = f16x2{(_Float16)b1a.z, (_Float16)b1a.w};
    b1h[2] = f16x2{(_Float16)b1b.x, (_Float16)b1b.y};
    b1h[3] = f16x2{(_Float16)b1b.z, (_Float16)b1b.w};
    w2h[0] = f16x2{(_Float16)w2a.x, (_Float16)w2a.y};
    w2h[1] = f16x2{(_Float16)w2a.z, (_Float16)w2a.w};
    w2h[2] = f16x2{(_Float16)w2b.x, (_Float16)w2b.y};
    w2h[3] = f16x2{(_Float16)w2b.z, (_Float16)w2b.w};
  }
  const f16x2 z2 = {(_Float16)0.f, (_Float16)0.f};
  const float b2v = b2[0];

  const int e0 = (blockIdx.x * 4 + wid) * 16;

  uint4 rs[4], rt_[4];
#pragma unroll
  for (int j = 0; j < 4; ++j) {
    const int ej = e0 + j * 4 + g;
    const int src = lm[ej];
    const int tgt = lm[NEDGES + ej];
    rs[j]  = *(const uint4*)(P + (size_t)src * 256 + c);
    rt_[j] = *(const uint4*)(P + (size_t)tgt * 256 + 128 + c);
  }
  float lsum = 0.f;
#pragma unroll
  for (int j = 0; j < 4; ++j) {
    float p = 0.f;
    const unsigned su[4] = {rs[j].x, rs[j].y, rs[j].z, rs[j].w};
    const unsigned tu[4] = {rt_[j].x, rt_[j].y, rt_[j].z, rt_[j].w};
#pragma unroll
    for (int h = 0; h < 4; ++h) {
      const f16x2 s = __builtin_bit_cast(f16x2, su[h]);
      const f16x2 tt = __builtin_bit_cast(f16x2, tu[h]);
      const f16x2 a = __builtin_elementwise_max(s + tt + b1h[h], z2);
      p = __builtin_amdgcn_fdot2(a, w2h[h], p, false);
    }
    p += __shfl_xor(p, 8, 64);
    p += __shfl_xor(p, 4, 64);
    p += __shfl_xor(p, 2, 64);
    p += __shfl_xor(p, 1, 64);
    if (l16 == j) {
      const float ev = __expf(p + b2v);
      explog[e0 + j * 4 + g] = ev;
      lsum += ev;
    }
  }

#pragma unroll
  for (int off = 32; off >= 1; off >>= 1) lsum += __shfl_xor(lsum, off, 64);
  __shared__ float wsums[4];
  if (lane == 0) wsums[wid] = lsum;
  __syncthreads();
  if (threadIdx.x == 0)
    atomicAdd(sum_accum, wsums[0] + wsums[1] + wsums[2] + wsums[3]);
}

// ---------------- Kernel 3: normalize ----------------
__global__ __launch_bounds__(256) void norm_kernel(
    const float* __restrict__ explog, const float* __restrict__ sum_accum,
    float* __restrict__ out) {
  const float inv = 1.0f / *sum_accum;
  const int i = (blockIdx.x * 256 + threadIdx.x) * 4;
  if (i < NEDGES) {
    floatx4 v = *(const floatx4*)(explog + i);
    v.x *= inv; v.y *= inv; v.z *= inv; v.w *= inv;
    *(floatx4*)(out + i) = v;
  }
}

extern "C" void kernel_launch(void* const* d_in, const int* in_sizes, int n_in,
                              void* d_out, int out_size, void* d_ws, size_t ws_size,
                              hipStream_t stream) {
  const float* emb = (const float*)d_in[0];
  const int*   lm  = (const int*)d_in[1];   // [2, 1M]: sources then targets
  const float* W1  = (const float*)d_in[2];
  const float* b1  = (const float*)d_in[3];
  const float* W2  = (const float*)d_in[4];
  const float* b2  = (const float*)d_in[5];
  float* out = (float*)d_out;

  char* ws = (char*)d_ws;
  __half* P     = (__half*)ws;                   // 51,200,000 B
  float* accum  = (float*)(ws + 51200000);       // 256 B
  float* explog = (float*)(ws + 51200256);       // 4,000,000 B
  short* Bhi    = (short*)(ws + 55200256);       // 65,536 B
  short* Blo    = (short*)(ws + 55265792);       // 65,536 B
  short* Ahi    = (short*)(ws + 55331328);       // 100032*128*2 = 25,608,192 B
  short* Alo    = (short*)(ws + 80939520);       // 25,608,192 B  (end 106.5 MB)

  prep_kernel<<<6266, 256, 0, stream>>>(emb, W1, Ahi, Alo, Bhi, Blo, accum);
  project_kernel<<<1563, 256, 0, stream>>>(Ahi, Alo, Bhi, Blo, P);
  edge_kernel<<<15625, 256, 0, stream>>>(P, lm, b1, W2, b2, explog, accum);
  norm_kernel<<<977, 256, 0, stream>>>(explog, accum, out);
}

// Round 7
// 227.108 us; speedup vs baseline: 1.5584x; 1.5584x over previous
//
#include <hip/hip_runtime.h>
#include <hip/hip_bf16.h>
#include <hip/hip_fp16.h>
#include <stdint.h>

#define NNODES 100000
#define HID 128
#define NEDGES 1000000
#define NEBLOCKS 15625  // edge blocks: 15625 * 4 waves * 16 edges = 1,000,000

typedef __attribute__((ext_vector_type(8))) short short8;
typedef __attribute__((ext_vector_type(4))) float floatx4;
typedef _Float16 f16x2 __attribute__((ext_vector_type(2)));

__device__ __forceinline__ unsigned short bf16_rn(float x) {
  unsigned u = __builtin_bit_cast(unsigned, x);
  u += 0x7fffu + ((u >> 16) & 1u);
  return (unsigned short)(u >> 16);
}
__device__ __forceinline__ float bf16_to_f(unsigned short h) {
  unsigned u = ((unsigned)h) << 16;
  return __builtin_bit_cast(float, u);
}

// ---------------- Kernel 0: prep ----------------
// blocks [0,6250): emb (fp32, 12.8M elems) -> Ahi/Alo bf16 hi/lo split,
//                  row-major [node][k] (flat copy, 8 elems/thread).
// blocks [6250,6266): pack B = [W1_top | W1_bot] into MFMA fragment order,
//                  bf16 hi/lo. Fragment: B[k=(lane>>4)*8+j][n=lane&15],
//                  element base ((ct*4+ks)*64+lane)*8.
__global__ __launch_bounds__(256) void prep_kernel(
    const float* __restrict__ emb, const float* __restrict__ W1,
    short* __restrict__ Ahi, short* __restrict__ Alo,
    short* __restrict__ Bhi, short* __restrict__ Blo) {
  const int b = blockIdx.x;
  if (b < 6250) {
    const size_t i = ((size_t)b * 256 + threadIdx.x) * 8;
    const floatx4 v0 = *(const floatx4*)(emb + i);
    const floatx4 v1 = *(const floatx4*)(emb + i + 4);
    float x[8] = {v0.x, v0.y, v0.z, v0.w, v1.x, v1.y, v1.z, v1.w};
    short8 h, l;
#pragma unroll
    for (int j = 0; j < 8; ++j) {
      const unsigned short hh = bf16_rn(x[j]);
      h[j] = (short)hh;
      l[j] = (short)bf16_rn(x[j] - bf16_to_f(hh));
    }
    *(short8*)(Ahi + i) = h;
    *(short8*)(Alo + i) = l;
  } else {
    const int t = (b - 6250) * 256 + threadIdx.x;  // 0..4095
    const int lane = t & 63;
    const int ks = (t >> 6) & 3;
    const int ct = t >> 8;
    const int n = ct * 16 + (lane & 15);
    const int kb = ks * 32 + ((lane >> 4) * 8);
    short8 h, l;
#pragma unroll
    for (int j = 0; j < 8; ++j) {
      const int k = kb + j;
      const float v = (n < HID) ? W1[(size_t)k * HID + n]
                                : W1[(size_t)(HID + k) * HID + (n - HID)];
      const unsigned short hh = bf16_rn(v);
      h[j] = (short)hh;
      l[j] = (short)bf16_rn(v - bf16_to_f(hh));
    }
    *(short8*)(Bhi + (size_t)t * 8) = h;
    *(short8*)(Blo + (size_t)t * 8) = l;
  }
}

// ---------------- Kernel 1: node projection via MFMA (bf16 hi/lo split) ----
// Block: 64 rows x 256 cols. A fragments read DIRECTLY from pre-split global
// Ahi/Alo (16B/lane, 128B lines fully consumed; 4 waves reuse via L1).
// No LDS, no barriers in the K-path. P[m][n] fp16 store via LDS epilogue.
__global__ __launch_bounds__(256) void project_kernel(
    const short* __restrict__ Ahi, const short* __restrict__ Alo,
    const short* __restrict__ Bhi, const short* __restrict__ Blo,
    __half* __restrict__ P) {
  __shared__ __half Co[64 * 264];  // 33792 B

  const int t = threadIdx.x;
  const int lane = t & 63;
  const int w = t >> 6;
  const int l16 = lane & 15;
  const int q = lane >> 4;
  const int row0 = blockIdx.x * 64;

  floatx4 acc[4][4] = {};  // [rt][ct]

#pragma unroll
  for (int ks = 0; ks < 4; ++ks) {
    short8 bh[4], bl[4];
#pragma unroll
    for (int ct = 0; ct < 4; ++ct) {
      const size_t idx = (size_t)(((w * 4 + ct) * 4 + ks) * 64 + lane) * 8;
      bh[ct] = *(const short8*)(Bhi + idx);
      bl[ct] = *(const short8*)(Blo + idx);
    }
#pragma unroll
    for (int rt = 0; rt < 4; ++rt) {
      const size_t la = (size_t)(row0 + rt * 16 + l16) * 128 + ks * 32 + q * 8;
      const short8 ah = *(const short8*)(Ahi + la);
      const short8 al = *(const short8*)(Alo + la);
#pragma unroll
      for (int ct = 0; ct < 4; ++ct) {
        acc[rt][ct] = __builtin_amdgcn_mfma_f32_16x16x32_bf16(ah, bh[ct], acc[rt][ct], 0, 0, 0);
        acc[rt][ct] = __builtin_amdgcn_mfma_f32_16x16x32_bf16(al, bh[ct], acc[rt][ct], 0, 0, 0);
        acc[rt][ct] = __builtin_amdgcn_mfma_f32_16x16x32_bf16(ah, bl[ct], acc[rt][ct], 0, 0, 0);
      }
    }
  }

  // epilogue: C/D layout col=lane&15, row=(lane>>4)*4+reg -> LDS -> coalesced.
#pragma unroll
  for (int rt = 0; rt < 4; ++rt)
#pragma unroll
    for (int ct = 0; ct < 4; ++ct)
#pragma unroll
      for (int r = 0; r < 4; ++r) {
        const int row = rt * 16 + q * 4 + r;
        const int col = w * 64 + ct * 16 + l16;
        Co[row * 264 + col] = __float2half(acc[rt][ct][r]);
      }
  __syncthreads();
#pragma unroll
  for (int i = 0; i < 8; ++i) {
    const int chunk = t + i * 256;  // 2048 chunks of 16B, 32 per row
    const int row = chunk >> 5;
    const int cx = chunk & 31;
    if (row0 + row < NNODES) {
      const floatx4 v = *(const floatx4*)&Co[row * 264 + cx * 8];
      *(floatx4*)(P + (size_t)(row0 + row) * 256 + cx * 8) = v;
    }
  }
}

// ---------------- Kernel 2: per-edge MLP + exp --------------------
// Exact-fit grid: 15625 blocks x 4 waves x 16 edges = 1,000,000. No loop,
// no bounds checks. 16 lanes/edge, 8 halfs/lane (dwordx4 gathers),
// packed-half math + v_dot2_f32_f16, 4-shuffle reduce per 4 edges.
// Block partial sum -> PLAIN STORE to partials[blockIdx.x] (no atomics).
__global__ __launch_bounds__(256) void edge_kernel(
    const __half* __restrict__ P, const int* __restrict__ lm,
    const float* __restrict__ b1, const float* __restrict__ W2,
    const float* __restrict__ b2, float* __restrict__ explog,
    float* __restrict__ partials) {
  const int lane = threadIdx.x & 63;
  const int wid = threadIdx.x >> 6;
  const int g = lane >> 4;    // edge sub-group 0..3
  const int l16 = lane & 15;
  const int c = l16 * 8;      // 8 halfs per lane

  f16x2 b1h[4], w2h[4];
  {
    const floatx4 b1a = *(const floatx4*)(b1 + c);
    const floatx4 b1b = *(const floatx4*)(b1 + c + 4);
    const floatx4 w2a = *(const floatx4*)(W2 + c);
    const floatx4 w2b = *(const floatx4*)(W2 + c + 4);
    b1h[0] = f16x2{(_Float16)b1a.x, (_Float16)b1a.y};
    b1h[1] = f16x2{(_Float16)b1a.z, (_Float16)b1a.w};
    b1h[2] = f16x2{(_Float16)b1b.x, (_Float16)b1b.y};
    b1h[3] = f16x2{(_Float16)b1b.z, (_Float16)b1b.w};
    w2h[0] = f16x2{(_Float16)w2a.x, (_Float16)w2a.y};
    w2h[1] = f16x2{(_Float16)w2a.z, (_Float16)w2a.w};
    w2h[2] = f16x2{(_Float16)w2b.x, (_Float16)w2b.y};
    w2h[3] = f16x2{(_Float16)w2b.z, (_Float16)w2b.w};
  }
  const f16x2 z2 = {(_Float16)0.f, (_Float16)0.f};
  const float b2v = b2[0];

  const int e0 = (blockIdx.x * 4 + wid) * 16;

  uint4 rs[4], rt_[4];
#pragma unroll
  for (int j = 0; j < 4; ++j) {
    const int ej = e0 + j * 4 + g;
    const int src = lm[ej];
    const int tgt = lm[NEDGES + ej];
    rs[j]  = *(const uint4*)(P + (size_t)src * 256 + c);
    rt_[j] = *(const uint4*)(P + (size_t)tgt * 256 + 128 + c);
  }
  float lsum = 0.f;
#pragma unroll
  for (int j = 0; j < 4; ++j) {
    float p = 0.f;
    const unsigned su[4] = {rs[j].x, rs[j].y, rs[j].z, rs[j].w};
    const unsigned tu[4] = {rt_[j].x, rt_[j].y, rt_[j].z, rt_[j].w};
#pragma unroll
    for (int h = 0; h < 4; ++h) {
      const f16x2 s = __builtin_bit_cast(f16x2, su[h]);
      const f16x2 tt = __builtin_bit_cast(f16x2, tu[h]);
      const f16x2 a = __builtin_elementwise_max(s + tt + b1h[h], z2);
      p = __builtin_amdgcn_fdot2(a, w2h[h], p, false);
    }
    p += __shfl_xor(p, 8, 64);
    p += __shfl_xor(p, 4, 64);
    p += __shfl_xor(p, 2, 64);
    p += __shfl_xor(p, 1, 64);
    if (l16 == j) {
      const float ev = __expf(p + b2v);
      explog[e0 + j * 4 + g] = ev;
      lsum += ev;
    }
  }

#pragma unroll
  for (int off = 32; off >= 1; off >>= 1) lsum += __shfl_xor(lsum, off, 64);
  __shared__ float wsums[4];
  if (lane == 0) wsums[wid] = lsum;
  __syncthreads();
  if (threadIdx.x == 0)
    partials[blockIdx.x] = wsums[0] + wsums[1] + wsums[2] + wsums[3];
}

// ---------------- Kernel 2.5: reduce partials -> accum (single block) ------
__global__ __launch_bounds__(256) void reduce_kernel(
    const float* __restrict__ partials, float* __restrict__ accum) {
  float s = 0.f;
  for (int i = threadIdx.x; i < NEBLOCKS; i += 256) s += partials[i];
#pragma unroll
  for (int off = 32; off >= 1; off >>= 1) s += __shfl_xor(s, off, 64);
  __shared__ float ws_[4];
  if ((threadIdx.x & 63) == 0) ws_[threadIdx.x >> 6] = s;
  __syncthreads();
  if (threadIdx.x == 0) accum[0] = ws_[0] + ws_[1] + ws_[2] + ws_[3];
}

// ---------------- Kernel 3: normalize ----------------
__global__ __launch_bounds__(256) void norm_kernel(
    const float* __restrict__ explog, const float* __restrict__ sum_accum,
    float* __restrict__ out) {
  const float inv = 1.0f / *sum_accum;
  const int i = (blockIdx.x * 256 + threadIdx.x) * 4;
  if (i < NEDGES) {
    floatx4 v = *(const floatx4*)(explog + i);
    v.x *= inv; v.y *= inv; v.z *= inv; v.w *= inv;
    *(floatx4*)(out + i) = v;
  }
}

extern "C" void kernel_launch(void* const* d_in, const int* in_sizes, int n_in,
                              void* d_out, int out_size, void* d_ws, size_t ws_size,
                              hipStream_t stream) {
  const float* emb = (const float*)d_in[0];
  const int*   lm  = (const int*)d_in[1];   // [2, 1M]: sources then targets
  const float* W1  = (const float*)d_in[2];
  const float* b1  = (const float*)d_in[3];
  const float* W2  = (const float*)d_in[4];
  const float* b2  = (const float*)d_in[5];
  float* out = (float*)d_out;

  char* ws = (char*)d_ws;
  __half* P      = (__half*)ws;                   // 51,200,000 B
  float* accum   = (float*)(ws + 51200000);       // 256 B
  float* explog  = (float*)(ws + 51200256);       // 4,000,000 B
  short* Bhi     = (short*)(ws + 55200256);       // 65,536 B
  short* Blo     = (short*)(ws + 55265792);       // 65,536 B
  short* Ahi     = (short*)(ws + 55331328);       // 100032*128*2 = 25,608,192 B
  short* Alo     = (short*)(ws + 80939520);       // 25,608,192 B
  float* partials = (float*)(ws + 106547712);     // 15625*4 = 62,500 B

  prep_kernel<<<6266, 256, 0, stream>>>(emb, W1, Ahi, Alo, Bhi, Blo);
  project_kernel<<<1563, 256, 0, stream>>>(Ahi, Alo, Bhi, Blo, P);
  edge_kernel<<<NEBLOCKS, 256, 0, stream>>>(P, lm, b1, W2, b2, explog, partials);
  reduce_kernel<<<1, 256, 0, stream>>>(partials, accum);
  norm_kernel<<<977, 256, 0, stream>>>(explog, accum, out);
}

// Round 8
// 209.596 us; speedup vs baseline: 1.6886x; 1.0835x over previous
//
#include <hip/hip_runtime.h>
#include <hip/hip_bf16.h>
#include <hip/hip_fp16.h>
#include <stdint.h>

#define NNODES 100000
#define HID 128
#define NEDGES 1000000
#define NEBLOCKS 7813  // edge blocks: 7813 * 4 waves * 32 edges >= 1,000,000

typedef __attribute__((ext_vector_type(8))) short short8;
typedef __attribute__((ext_vector_type(4))) float floatx4;
typedef _Float16 f16x2 __attribute__((ext_vector_type(2)));

__device__ __forceinline__ unsigned short bf16_rn(float x) {
  unsigned u = __builtin_bit_cast(unsigned, x);
  u += 0x7fffu + ((u >> 16) & 1u);
  return (unsigned short)(u >> 16);
}
__device__ __forceinline__ float bf16_to_f(unsigned short h) {
  unsigned u = ((unsigned)h) << 16;
  return __builtin_bit_cast(float, u);
}

// ---------------- Kernel 0: pack B = [W1_top | W1_bot] into MFMA fragment
// order, bf16 hi/lo split. Fragment: B[k=(lane>>4)*8+j][n=lane&15],
// element base ((ct*4+ks)*64+lane)*8, ct=0..15 (16-col tiles), ks=0..3.
__global__ __launch_bounds__(256) void pack_b_kernel(
    const float* __restrict__ W1, short* __restrict__ Bhi,
    short* __restrict__ Blo) {
  const int t = blockIdx.x * 256 + threadIdx.x;  // 0..4095
  const int lane = t & 63;
  const int ks = (t >> 6) & 3;
  const int ct = t >> 8;
  const int n = ct * 16 + (lane & 15);
  const int kb = ks * 32 + ((lane >> 4) * 8);
  short8 h, l;
#pragma unroll
  for (int j = 0; j < 8; ++j) {
    const int k = kb + j;
    const float v = (n < HID) ? W1[(size_t)k * HID + n]
                              : W1[(size_t)(HID + k) * HID + (n - HID)];
    const unsigned short hh = bf16_rn(v);
    h[j] = (short)hh;
    l[j] = (short)bf16_rn(v - bf16_to_f(hh));
  }
  *(short8*)(Bhi + (size_t)t * 8) = h;
  *(short8*)(Blo + (size_t)t * 8) = l;
}

// ---------------- Kernel 1: node projection via MFMA (bf16 hi/lo split) ----
// Block: 64 rows x 256 cols. A fragments loaded DIRECTLY from emb as fp32
// (2 dwordx4 per fragment, in-register hi/lo bf16 convert; each block reads
// its 32KB of emb once per wave, 4 waves reuse via L1). No prep pass, no LDS
// in the K-path. P[m][n] fp16 store via LDS epilogue.
__global__ __launch_bounds__(256) void project_kernel(
    const float* __restrict__ emb, const short* __restrict__ Bhi,
    const short* __restrict__ Blo, __half* __restrict__ P) {
  __shared__ __half Co[64 * 264];  // 33792 B

  const int t = threadIdx.x;
  const int lane = t & 63;
  const int w = t >> 6;
  const int l16 = lane & 15;
  const int q = lane >> 4;
  const int row0 = blockIdx.x * 64;

  floatx4 acc[4][4] = {};  // [rt][ct]

  // per-lane A row (clamped so tail-block loads stay in-bounds; those rows
  // produce garbage accs that the epilogue never stores)
  int arow[4];
#pragma unroll
  for (int rt = 0; rt < 4; ++rt) {
    int r = row0 + rt * 16 + l16;
    arow[rt] = (r < NNODES) ? r : (NNODES - 1);
  }

#pragma unroll
  for (int ks = 0; ks < 4; ++ks) {
    short8 bh[4], bl[4];
#pragma unroll
    for (int ct = 0; ct < 4; ++ct) {
      const size_t idx = (size_t)(((w * 4 + ct) * 4 + ks) * 64 + lane) * 8;
      bh[ct] = *(const short8*)(Bhi + idx);
      bl[ct] = *(const short8*)(Blo + idx);
    }
    floatx4 a0[4], a1[4];
#pragma unroll
    for (int rt = 0; rt < 4; ++rt) {
      const float* ap = emb + (size_t)arow[rt] * HID + ks * 32 + q * 8;
      a0[rt] = *(const floatx4*)ap;
      a1[rt] = *(const floatx4*)(ap + 4);
    }
#pragma unroll
    for (int rt = 0; rt < 4; ++rt) {
      const float x[8] = {a0[rt].x, a0[rt].y, a0[rt].z, a0[rt].w,
                          a1[rt].x, a1[rt].y, a1[rt].z, a1[rt].w};
      short8 ah, al;
#pragma unroll
      for (int j = 0; j < 8; ++j) {
        const unsigned short hh = bf16_rn(x[j]);
        ah[j] = (short)hh;
        al[j] = (short)bf16_rn(x[j] - bf16_to_f(hh));
      }
#pragma unroll
      for (int ct = 0; ct < 4; ++ct) {
        acc[rt][ct] = __builtin_amdgcn_mfma_f32_16x16x32_bf16(ah, bh[ct], acc[rt][ct], 0, 0, 0);
        acc[rt][ct] = __builtin_amdgcn_mfma_f32_16x16x32_bf16(al, bh[ct], acc[rt][ct], 0, 0, 0);
        acc[rt][ct] = __builtin_amdgcn_mfma_f32_16x16x32_bf16(ah, bl[ct], acc[rt][ct], 0, 0, 0);
      }
    }
  }

  // epilogue: C/D layout col=lane&15, row=(lane>>4)*4+reg -> LDS -> coalesced.
#pragma unroll
  for (int rt = 0; rt < 4; ++rt)
#pragma unroll
    for (int ct = 0; ct < 4; ++ct)
#pragma unroll
      for (int r = 0; r < 4; ++r) {
        const int row = rt * 16 + q * 4 + r;
        const int col = w * 64 + ct * 16 + l16;
        Co[row * 264 + col] = __float2half(acc[rt][ct][r]);
      }
  __syncthreads();
#pragma unroll
  for (int i = 0; i < 8; ++i) {
    const int chunk = t + i * 256;  // 2048 chunks of 16B, 32 per row
    const int row = chunk >> 5;
    const int cx = chunk & 31;
    if (row0 + row < NNODES) {
      const floatx4 v = *(const floatx4*)&Co[row * 264 + cx * 8];
      *(floatx4*)(P + (size_t)(row0 + row) * 256 + cx * 8) = v;
    }
  }
}

// ---------------- Kernel 2: per-edge MLP + exp --------------------
// 7813 blocks x 4 waves x 32 edges (last wave-group predicated). 16 lanes per
// edge, 8 halfs/lane; 16 dwordx4 gathers issued up front (2x R7's ILP).
// Packed-half math + v_dot2_f32_f16, 4-shuffle reduce per 4 edges.
// Block partial sum -> plain store to partials[blockIdx.x] (no atomics).
__global__ __launch_bounds__(256) void edge_kernel(
    const __half* __restrict__ P, const int* __restrict__ lm,
    const float* __restrict__ b1, const float* __restrict__ W2,
    const float* __restrict__ b2, float* __restrict__ explog,
    float* __restrict__ partials) {
  const int lane = threadIdx.x & 63;
  const int wid = threadIdx.x >> 6;
  const int g = lane >> 4;    // edge sub-group 0..3
  const int l16 = lane & 15;
  const int c = l16 * 8;      // 8 halfs per lane

  f16x2 b1h[4], w2h[4];
  {
    const floatx4 b1a = *(const floatx4*)(b1 + c);
    const floatx4 b1b = *(const floatx4*)(b1 + c + 4);
    const floatx4 w2a = *(const floatx4*)(W2 + c);
    const floatx4 w2b = *(const floatx4*)(W2 + c + 4);
    b1h[0] = f16x2{(_Float16)b1a.x, (_Float16)b1a.y};
    b1h[1] = f16x2{(_Float16)b1a.z, (_Float16)b1a.w};
    b1h[2] = f16x2{(_Float16)b1b.x, (_Float16)b1b.y};
    b1h[3] = f16x2{(_Float16)b1b.z, (_Float16)b1b.w};
    w2h[0] = f16x2{(_Float16)w2a.x, (_Float16)w2a.y};
    w2h[1] = f16x2{(_Float16)w2a.z, (_Float16)w2a.w};
    w2h[2] = f16x2{(_Float16)w2b.x, (_Float16)w2b.y};
    w2h[3] = f16x2{(_Float16)w2b.z, (_Float16)w2b.w};
  }
  const f16x2 z2 = {(_Float16)0.f, (_Float16)0.f};
  const float b2v = b2[0];

  const int e0 = (blockIdx.x * 4 + wid) * 32;

  uint4 rs[8], rt_[8];
#pragma unroll
  for (int j = 0; j < 8; ++j) {
    int ej = e0 + j * 4 + g;
    if (ej >= NEDGES) ej = NEDGES - 1;
    const int src = lm[ej];
    const int tgt = lm[NEDGES + ej];
    rs[j]  = *(const uint4*)(P + (size_t)src * 256 + c);
    rt_[j] = *(const uint4*)(P + (size_t)tgt * 256 + 128 + c);
  }
  float lsum = 0.f;
#pragma unroll
  for (int j = 0; j < 8; ++j) {
    float p = 0.f;
    const unsigned su[4] = {rs[j].x, rs[j].y, rs[j].z, rs[j].w};
    const unsigned tu[4] = {rt_[j].x, rt_[j].y, rt_[j].z, rt_[j].w};
#pragma unroll
    for (int h = 0; h < 4; ++h) {
      const f16x2 s = __builtin_bit_cast(f16x2, su[h]);
      const f16x2 tt = __builtin_bit_cast(f16x2, tu[h]);
      const f16x2 a = __builtin_elementwise_max(s + tt + b1h[h], z2);
      p = __builtin_amdgcn_fdot2(a, w2h[h], p, false);
    }
    p += __shfl_xor(p, 8, 64);
    p += __shfl_xor(p, 4, 64);
    p += __shfl_xor(p, 2, 64);
    p += __shfl_xor(p, 1, 64);
    if (l16 == j) {
      const int ej = e0 + j * 4 + g;
      if (ej < NEDGES) {
        const float ev = __expf(p + b2v);
        explog[ej] = ev;
        lsum += ev;
      }
    }
  }

#pragma unroll
  for (int off = 32; off >= 1; off >>= 1) lsum += __shfl_xor(lsum, off, 64);
  __shared__ float wsums[4];
  if (lane == 0) wsums[wid] = lsum;
  __syncthreads();
  if (threadIdx.x == 0)
    partials[blockIdx.x] = wsums[0] + wsums[1] + wsums[2] + wsums[3];
}

// ---------------- Kernel 2.5: reduce partials -> accum (single block) ------
__global__ __launch_bounds__(256) void reduce_kernel(
    const float* __restrict__ partials, float* __restrict__ accum) {
  float s = 0.f;
  for (int i = threadIdx.x; i < NEBLOCKS; i += 256) s += partials[i];
#pragma unroll
  for (int off = 32; off >= 1; off >>= 1) s += __shfl_xor(s, off, 64);
  __shared__ float ws_[4];
  if ((threadIdx.x & 63) == 0) ws_[threadIdx.x >> 6] = s;
  __syncthreads();
  if (threadIdx.x == 0) accum[0] = ws_[0] + ws_[1] + ws_[2] + ws_[3];
}

// ---------------- Kernel 3: normalize ----------------
__global__ __launch_bounds__(256) void norm_kernel(
    const float* __restrict__ explog, const float* __restrict__ sum_accum,
    float* __restrict__ out) {
  const float inv = 1.0f / *sum_accum;
  const int i = (blockIdx.x * 256 + threadIdx.x) * 4;
  if (i < NEDGES) {
    floatx4 v = *(const floatx4*)(explog + i);
    v.x *= inv; v.y *= inv; v.z *= inv; v.w *= inv;
    *(floatx4*)(out + i) = v;
  }
}

extern "C" void kernel_launch(void* const* d_in, const int* in_sizes, int n_in,
                              void* d_out, int out_size, void* d_ws, size_t ws_size,
                              hipStream_t stream) {
  const float* emb = (const float*)d_in[0];
  const int*   lm  = (const int*)d_in[1];   // [2, 1M]: sources then targets
  const float* W1  = (const float*)d_in[2];
  const float* b1  = (const float*)d_in[3];
  const float* W2  = (const float*)d_in[4];
  const float* b2  = (const float*)d_in[5];
  float* out = (float*)d_out;

  char* ws = (char*)d_ws;
  __half* P       = (__half*)ws;                   // 51,200,000 B
  float* accum    = (float*)(ws + 51200000);       // 256 B
  float* explog   = (float*)(ws + 51200256);       // 4,000,000 B
  short* Bhi      = (short*)(ws + 55200256);       // 65,536 B
  short* Blo      = (short*)(ws + 55265792);       // 65,536 B
  float* partials = (float*)(ws + 55331328);       // 7813*4 B

  pack_b_kernel<<<16, 256, 0, stream>>>(W1, Bhi, Blo);
  project_kernel<<<1563, 256, 0, stream>>>(emb, Bhi, Blo, P);
  edge_kernel<<<NEBLOCKS, 256, 0, stream>>>(P, lm, b1, W2, b2, explog, partials);
  reduce_kernel<<<1, 256, 0, stream>>>(partials, accum);
  norm_kernel<<<977, 256, 0, stream>>>(explog, accum, out);
}